// Round 2
// baseline (1133.528 us; speedup 1.0000x reference)
//
#include <hip/hip_runtime.h>

#define N_NODES 50000
#define N_EDGES 625000
#define D 128
#define GR 32   // rows per GEMM block

// ---- degree count on dst (self-loop added as +1 later) ----
__global__ void k_deg(const int* __restrict__ dst, int* __restrict__ deg) {
    int e = blockIdx.x * 256 + threadIdx.x;
    if (e < N_EDGES) atomicAdd(&deg[dst[e]], 1);
}

__global__ void k_dinv(const int* __restrict__ deg, float* __restrict__ dinv) {
    int i = blockIdx.x * 256 + threadIdx.x;
    if (i < N_NODES) dinv[i] = rsqrtf((float)(deg[i] + 1));  // +1 self loop; deg>=1 always
}

// agg[n] = dinv[n]^2 * x[n]  (self-loop term; also fully initializes ws agg)
__global__ void k_agg_init(const float* __restrict__ x, const float* __restrict__ dinv,
                           float* __restrict__ agg) {
    int i = blockIdx.x * 256 + threadIdx.x;  // float2 index
    if (i < N_NODES * (D / 2)) {
        int n = i / (D / 2);
        float s = dinv[n];
        s = s * s;
        float2 v = ((const float2*)x)[i];
        ((float2*)agg)[i] = make_float2(s * v.x, s * v.y);
    }
}

// one wave per edge: agg[dst] += dinv[src]*dinv[dst] * x[src]
__global__ void k_scatter(const int* __restrict__ src, const int* __restrict__ dst,
                          const float* __restrict__ x, const float* __restrict__ dinv,
                          float* __restrict__ agg) {
    int wid = (blockIdx.x * 256 + threadIdx.x) >> 6;  // wave id == edge id
    int lane = threadIdx.x & 63;
    if (wid >= N_EDGES) return;
    int s = src[wid];
    int d = dst[wid];
    float nrm = dinv[s] * dinv[d];
    float2 v = ((const float2*)(x + (size_t)s * D))[lane];
    float* o = agg + (size_t)d * D + lane * 2;
    atomicAdd(o, nrm * v.x);
    atomicAdd(o + 1, nrm * v.y);
}

// wT[k][c] = w[c][k]  (once; makes GEMM LDS loads linear + reads conflict-free)
__global__ void k_wT(const float* __restrict__ w, float* __restrict__ wT) {
    int i = blockIdx.x * 256 + threadIdx.x;  // 16384 elements
    if (i < D * D) {
        int c = i >> 7, k = i & 127;
        wT[k * D + c] = w[i];
    }
}

// out[r][c] = sum_k agg[r][k] * wT[k][c] + bias[c]
__global__ __launch_bounds__(256) void k_gemm(const float* __restrict__ agg,
                                              const float* __restrict__ wT,
                                              const float* __restrict__ bias,
                                              float* __restrict__ out) {
    __shared__ float a_lds[GR][D];   // 16 KB
    __shared__ float w_lds[D][D];    // 64 KB
    int t = threadIdx.x;
    int row0 = blockIdx.x * GR;

    // stage wT (linear copy, coalesced, conflict-free)
    #pragma unroll
    for (int j = 0; j < (D * D) / (256 * 4); ++j) {  // 16 iters
        int fi = t + 256 * j;
        ((float4*)w_lds)[fi] = ((const float4*)wT)[fi];
    }
    // stage a tile with tail guard
    #pragma unroll
    for (int j = 0; j < (GR * D) / (256 * 4); ++j) {  // 4 iters
        int fi = t + 256 * j;
        int gelem = row0 * D + fi * 4;
        float4 v = (gelem + 3 < N_NODES * D) ? ((const float4*)agg)[(row0 * D) / 4 + fi]
                                             : make_float4(0.f, 0.f, 0.f, 0.f);
        ((float4*)a_lds)[fi] = v;
    }
    __syncthreads();

    int tc = t & 31;       // col group: cols 4*tc .. 4*tc+3
    int tg = t >> 5;       // row group: rows tg*4 .. tg*4+3
    int c0 = tc * 4;

    float4 acc[4];
    #pragma unroll
    for (int r = 0; r < 4; ++r) acc[r] = make_float4(0.f, 0.f, 0.f, 0.f);

    #pragma unroll
    for (int k = 0; k < D; k += 4) {
        float4 w0 = *(const float4*)&w_lds[k + 0][c0];
        float4 w1 = *(const float4*)&w_lds[k + 1][c0];
        float4 w2 = *(const float4*)&w_lds[k + 2][c0];
        float4 w3 = *(const float4*)&w_lds[k + 3][c0];
        #pragma unroll
        for (int r = 0; r < 4; ++r) {
            float4 av = *(const float4*)&a_lds[tg * 4 + r][k];
            acc[r].x += av.x * w0.x + av.y * w1.x + av.z * w2.x + av.w * w3.x;
            acc[r].y += av.x * w0.y + av.y * w1.y + av.z * w2.y + av.w * w3.y;
            acc[r].z += av.x * w0.z + av.y * w1.z + av.z * w2.z + av.w * w3.z;
            acc[r].w += av.x * w0.w + av.y * w1.w + av.z * w2.w + av.w * w3.w;
        }
    }

    float4 bv = ((const float4*)bias)[tc];
    #pragma unroll
    for (int r = 0; r < 4; ++r) {
        int row = row0 + tg * 4 + r;
        if (row < N_NODES) {
            float4 o = make_float4(acc[r].x + bv.x, acc[r].y + bv.y,
                                   acc[r].z + bv.z, acc[r].w + bv.w);
            ((float4*)(out + (size_t)row * D))[tc] = o;
        }
    }
}

extern "C" void kernel_launch(void* const* d_in, const int* in_sizes, int n_in,
                              void* d_out, int out_size, void* d_ws, size_t ws_size,
                              hipStream_t stream) {
    const float* x    = (const float*)d_in[0];
    const int*   ei   = (const int*)d_in[1];   // [2, E] flat: row0=src, row1=dst
    const float* w    = (const float*)d_in[2];
    const float* bias = (const float*)d_in[3];
    float* out = (float*)d_out;

    // workspace carve
    float* agg  = (float*)d_ws;                                   // N*D f32 = 25.6 MB
    int*   deg  = (int*)((char*)d_ws + (size_t)N_NODES * D * 4);  // N int
    float* dinv = (float*)(deg + N_NODES);                        // N f32
    float* wT   = dinv + N_NODES;                                 // D*D f32

    const int* src = ei;
    const int* dst = ei + N_EDGES;

    hipMemsetAsync(deg, 0, N_NODES * sizeof(int), stream);
    k_deg<<<(N_EDGES + 255) / 256, 256, 0, stream>>>(dst, deg);
    k_dinv<<<(N_NODES + 255) / 256, 256, 0, stream>>>(deg, dinv);
    k_wT<<<(D * D + 255) / 256, 256, 0, stream>>>(w, wT);
    k_agg_init<<<(N_NODES * (D / 2) + 255) / 256, 256, 0, stream>>>(x, dinv, agg);
    k_scatter<<<(N_EDGES * 64) / 256, 256, 0, stream>>>(src, dst, x, dinv, agg);
    k_gemm<<<(N_NODES + GR - 1) / GR, 256, 0, stream>>>(agg, wT, bias, out);
}

// Round 3
// 159.077 us; speedup vs baseline: 7.1257x; 7.1257x over previous
//
#include <hip/hip_runtime.h>
#include <hip/hip_bf16.h>

#define N_NODES 50000
#define N_EDGES 625000
#define D 128
#define SCAN_T 256
#define SCAN_ELEMS 1024
#define NB_SCAN ((N_NODES + SCAN_ELEMS - 1) / SCAN_ELEMS)  // 49

typedef __attribute__((ext_vector_type(8))) short bf16x8;
typedef __attribute__((ext_vector_type(4))) float f32x4;

// ---- in-degree histogram on dst (self-loop accounted as +1 in k_dinv) ----
__global__ void k_deg(const int* __restrict__ dst, int* __restrict__ deg) {
    int e = blockIdx.x * 256 + threadIdx.x;
    if (e < N_EDGES) atomicAdd(&deg[dst[e]], 1);
}

__global__ void k_dinv(const int* __restrict__ deg, float* __restrict__ dinv) {
    int i = blockIdx.x * 256 + threadIdx.x;
    if (i < N_NODES) dinv[i] = rsqrtf((float)(deg[i] + 1));
}

// ---- exclusive prefix sum of deg -> rowptr (3-step scan) ----
__global__ void k_scan1(const int* __restrict__ deg, int* __restrict__ part,
                        int* __restrict__ bsum) {
    __shared__ int ts[SCAN_T];
    int t = threadIdx.x;
    int base = blockIdx.x * SCAN_ELEMS + t * 4;
    int v0 = 0, v1 = 0, v2 = 0, v3 = 0;
    if (base + 0 < N_NODES) v0 = deg[base + 0];
    if (base + 1 < N_NODES) v1 = deg[base + 1];
    if (base + 2 < N_NODES) v2 = deg[base + 2];
    if (base + 3 < N_NODES) v3 = deg[base + 3];
    int s = v0 + v1 + v2 + v3;
    ts[t] = s;
    __syncthreads();
    for (int off = 1; off < SCAN_T; off <<= 1) {
        int tmp = 0;
        if (t >= off) tmp = ts[t - off];
        __syncthreads();
        if (t >= off) ts[t] += tmp;
        __syncthreads();
    }
    int excl = ts[t] - s;
    if (base + 0 < N_NODES) part[base + 0] = excl;
    if (base + 1 < N_NODES) part[base + 1] = excl + v0;
    if (base + 2 < N_NODES) part[base + 2] = excl + v0 + v1;
    if (base + 3 < N_NODES) part[base + 3] = excl + v0 + v1 + v2;
    if (t == SCAN_T - 1) bsum[blockIdx.x] = ts[t];
}

__global__ void k_scan2(const int* __restrict__ bsum, int* __restrict__ boff) {
    if (threadIdx.x == 0) {
        int run = 0;
        for (int b = 0; b < NB_SCAN; ++b) { int s = bsum[b]; boff[b] = run; run += s; }
    }
}

__global__ void k_scan3(const int* __restrict__ part, const int* __restrict__ boff,
                        int* __restrict__ rowptr, int* __restrict__ cur) {
    int i = blockIdx.x * 256 + threadIdx.x;
    if (i < N_NODES) {
        int r = part[i] + boff[i / SCAN_ELEMS];
        rowptr[i] = r;
        cur[i] = r;
    }
}

// ---- CSR fill: col[slot] = src, slots handed out by per-dst cursor ----
__global__ void k_fill(const int* __restrict__ src, const int* __restrict__ dst,
                       int* __restrict__ cur, int* __restrict__ col) {
    int e = blockIdx.x * 256 + threadIdx.x;
    if (e < N_EDGES) {
        int p = atomicAdd(&cur[dst[e]], 1);
        col[p] = src[e];
    }
}

__global__ void k_wbf16(const float* __restrict__ w, __hip_bfloat16* __restrict__ wb) {
    int i = blockIdx.x * 256 + threadIdx.x;
    if (i < D * D) wb[i] = __float2bfloat16(w[i]);
}

// ---- gather: half-wave (32 lanes, float4/lane = 512B row) per node ----
// agg[d] = dinv[d] * ( sum_e dinv[src_e]*x[src_e] + dinv[d]*x[d] ), written bf16
__global__ __launch_bounds__(256) void k_gather(const float* __restrict__ x,
                                                const float* __restrict__ dinv,
                                                const int* __restrict__ rowptr,
                                                const int* __restrict__ deg,
                                                const int* __restrict__ col,
                                                __hip_bfloat16* __restrict__ aggb) {
    int tid = blockIdx.x * 256 + threadIdx.x;
    int n = tid >> 5;            // node id (one per 32-lane half-wave)
    int sub = threadIdx.x & 31;  // float4 slot within the 128-wide row
    if (n >= N_NODES) return;
    float dd = dinv[n];
    float4 acc = ((const float4*)(x + (size_t)n * D))[sub];
    acc.x *= dd; acc.y *= dd; acc.z *= dd; acc.w *= dd;  // self-loop term (pre dd-scale)
    int rp = rowptr[n];
    int dn = deg[n];
    for (int j = 0; j < dn; ++j) {
        int s = col[rp + j];
        float ds = dinv[s];
        float4 v = ((const float4*)(x + (size_t)s * D))[sub];
        acc.x += ds * v.x; acc.y += ds * v.y; acc.z += ds * v.z; acc.w += ds * v.w;
    }
    acc.x *= dd; acc.y *= dd; acc.z *= dd; acc.w *= dd;
    union { __hip_bfloat162 h; unsigned u; } c0, c1;
    c0.h.x = __float2bfloat16(acc.x); c0.h.y = __float2bfloat16(acc.y);
    c1.h.x = __float2bfloat16(acc.z); c1.h.y = __float2bfloat16(acc.w);
    uint2 pk; pk.x = c0.u; pk.y = c1.u;
    ((uint2*)(aggb + (size_t)n * D))[sub] = pk;
}

// ---- GEMM: out[r][c] = sum_k agg[r][k]*w[c][k] + bias[c], bf16 MFMA ----
// 256 thr = 4 waves; wave w: 16 rows x cols [w*32, w*32+32); K=128 in 4 steps.
// Fragments: X[l&15][(l>>4)*8 + j] contiguous-k 16B loads (verified m92 B^T pattern).
__global__ __launch_bounds__(256) void k_gemm(const short* __restrict__ aggb,
                                              const short* __restrict__ wb,
                                              const float* __restrict__ bias,
                                              float* __restrict__ out) {
    int t = threadIdx.x;
    int wave = t >> 6, lane = t & 63;
    int row0 = blockIdx.x * 16;   // 3125 * 16 = 50000 exact
    int c0 = wave * 32;
    int lr = lane & 15;
    int lk = (lane >> 4) * 8;
    f32x4 acc0 = {0.f, 0.f, 0.f, 0.f};
    f32x4 acc1 = {0.f, 0.f, 0.f, 0.f};
    const short* ap  = aggb + (size_t)(row0 + lr) * D + lk;
    const short* bp0 = wb + (size_t)(c0 + lr) * D + lk;
    const short* bp1 = wb + (size_t)(c0 + 16 + lr) * D + lk;
    #pragma unroll
    for (int ks = 0; ks < 4; ++ks) {
        bf16x8 a  = *(const bf16x8*)(ap  + ks * 32);
        bf16x8 b0 = *(const bf16x8*)(bp0 + ks * 32);
        bf16x8 b1 = *(const bf16x8*)(bp1 + ks * 32);
        acc0 = __builtin_amdgcn_mfma_f32_16x16x32_bf16(a, b0, acc0, 0, 0, 0);
        acc1 = __builtin_amdgcn_mfma_f32_16x16x32_bf16(a, b1, acc1, 0, 0, 0);
    }
    // D layout: col = lane&15, row = (lane>>4)*4 + i  (m89-verified)
    int orow = row0 + (lane >> 4) * 4;
    int oc0 = c0 + lr, oc1 = c0 + 16 + lr;
    float bb0 = bias[oc0], bb1 = bias[oc1];
    #pragma unroll
    for (int i = 0; i < 4; ++i) {
        out[(size_t)(orow + i) * D + oc0] = acc0[i] + bb0;
        out[(size_t)(orow + i) * D + oc1] = acc1[i] + bb1;
    }
}

extern "C" void kernel_launch(void* const* d_in, const int* in_sizes, int n_in,
                              void* d_out, int out_size, void* d_ws, size_t ws_size,
                              hipStream_t stream) {
    const float* x    = (const float*)d_in[0];
    const int*   ei   = (const int*)d_in[1];   // [2, E] flat: row0=src, row1=dst
    const float* w    = (const float*)d_in[2];
    const float* bias = (const float*)d_in[3];
    float* out = (float*)d_out;

    const int* src = ei;
    const int* dst = ei + N_EDGES;

    // workspace carve (all regions fully rewritten every call)
    char* p = (char*)d_ws;
    __hip_bfloat16* aggb = (__hip_bfloat16*)p;       p += (size_t)N_NODES * D * 2;  // 12.8 MB
    __hip_bfloat16* wb   = (__hip_bfloat16*)p;       p += (size_t)D * D * 2;        // 32 KB
    int* deg    = (int*)p;  p += (size_t)N_NODES * 4;
    float* dinv = (float*)p; p += (size_t)N_NODES * 4;
    int* rowptr = (int*)p;  p += (size_t)N_NODES * 4;
    int* cur    = (int*)p;  p += (size_t)N_NODES * 4;
    int* part   = (int*)p;  p += (size_t)N_NODES * 4;
    int* col    = (int*)p;  p += (size_t)N_EDGES * 4;                               // 2.5 MB
    int* bsum   = (int*)p;  p += 256 * 4;
    int* boff   = (int*)p;  p += 256 * 4;

    hipMemsetAsync(deg, 0, N_NODES * sizeof(int), stream);
    k_deg<<<(N_EDGES + 255) / 256, 256, 0, stream>>>(dst, deg);
    k_dinv<<<(N_NODES + 255) / 256, 256, 0, stream>>>(deg, dinv);
    k_scan1<<<NB_SCAN, SCAN_T, 0, stream>>>(deg, part, bsum);
    k_scan2<<<1, 64, 0, stream>>>(bsum, boff);
    k_scan3<<<(N_NODES + 255) / 256, 256, 0, stream>>>(part, boff, rowptr, cur);
    k_fill<<<(N_EDGES + 255) / 256, 256, 0, stream>>>(src, dst, cur, col);
    k_wbf16<<<(D * D + 255) / 256, 256, 0, stream>>>(w, wb);
    k_gather<<<((N_NODES * 32) + 255) / 256, 256, 0, stream>>>(x, dinv, rowptr, deg, col, aggb);
    k_gemm<<<N_NODES / 16, 256, 0, stream>>>((const short*)aggb, (const short*)wb, bias, out);
}

// Round 4
// 146.004 us; speedup vs baseline: 7.7637x; 1.0895x over previous
//
#include <hip/hip_runtime.h>
#include <hip/hip_bf16.h>

#define N_NODES 50000
#define N_EDGES 625000
#define D 128
#define SCAN_T 256
#define SCAN_ELEMS 1024
#define NB_SCAN ((N_NODES + SCAN_ELEMS - 1) / SCAN_ELEMS)  // 49

typedef __attribute__((ext_vector_type(8))) short bf16x8;
typedef __attribute__((ext_vector_type(4))) float f32x4;

__device__ __forceinline__ float b2f(short s) {
    unsigned u = ((unsigned)(unsigned short)s) << 16;
    return __uint_as_float(u);
}
__device__ __forceinline__ short f2b(float f) {
    union { __hip_bfloat16 h; short s; } cv;
    cv.h = __float2bfloat16(f);
    return cv.s;
}

// ---- in-degree histogram on dst ----
__global__ void k_deg(const int* __restrict__ dst, int* __restrict__ deg) {
    int e = blockIdx.x * 256 + threadIdx.x;
    if (e < N_EDGES) atomicAdd(&deg[dst[e]], 1);
}

// ---- scan step 1 (+ fused dinv) ----
__global__ void k_scan1(const int* __restrict__ deg, int* __restrict__ part,
                        int* __restrict__ bsum, float* __restrict__ dinv) {
    __shared__ int ts[SCAN_T];
    int t = threadIdx.x;
    int base = blockIdx.x * SCAN_ELEMS + t * 4;
    int v0 = 0, v1 = 0, v2 = 0, v3 = 0;
    if (base + 0 < N_NODES) v0 = deg[base + 0];
    if (base + 1 < N_NODES) v1 = deg[base + 1];
    if (base + 2 < N_NODES) v2 = deg[base + 2];
    if (base + 3 < N_NODES) v3 = deg[base + 3];
    if (base + 0 < N_NODES) dinv[base + 0] = rsqrtf((float)(v0 + 1));
    if (base + 1 < N_NODES) dinv[base + 1] = rsqrtf((float)(v1 + 1));
    if (base + 2 < N_NODES) dinv[base + 2] = rsqrtf((float)(v2 + 1));
    if (base + 3 < N_NODES) dinv[base + 3] = rsqrtf((float)(v3 + 1));
    int s = v0 + v1 + v2 + v3;
    ts[t] = s;
    __syncthreads();
    for (int off = 1; off < SCAN_T; off <<= 1) {
        int tmp = 0;
        if (t >= off) tmp = ts[t - off];
        __syncthreads();
        if (t >= off) ts[t] += tmp;
        __syncthreads();
    }
    int excl = ts[t] - s;
    if (base + 0 < N_NODES) part[base + 0] = excl;
    if (base + 1 < N_NODES) part[base + 1] = excl + v0;
    if (base + 2 < N_NODES) part[base + 2] = excl + v0 + v1;
    if (base + 3 < N_NODES) part[base + 3] = excl + v0 + v1 + v2;
    if (t == SCAN_T - 1) bsum[blockIdx.x] = ts[t];
}

// ---- scan step 2: single-wave shfl prefix (was 1-thread serial loop) ----
__global__ void k_scan2(const int* __restrict__ bsum, int* __restrict__ boff) {
    int lane = threadIdx.x;  // 64 lanes, NB_SCAN=49 <= 64
    int v = (lane < NB_SCAN) ? bsum[lane] : 0;
    int orig = v;
    #pragma unroll
    for (int off = 1; off < 64; off <<= 1) {
        int tmp = __shfl_up(v, off);
        if (lane >= off) v += tmp;
    }
    if (lane < NB_SCAN) boff[lane] = v - orig;  // exclusive
}

__global__ void k_scan3(const int* __restrict__ part, const int* __restrict__ boff,
                        int* __restrict__ rowptr, int* __restrict__ cur) {
    int i = blockIdx.x * 256 + threadIdx.x;
    if (i < N_NODES) {
        int r = part[i] + boff[i / SCAN_ELEMS];
        rowptr[i] = r;
        cur[i] = r;
    }
}

// ---- CSR fill ----
__global__ void k_fill(const int* __restrict__ src, const int* __restrict__ dst,
                       int* __restrict__ cur, int* __restrict__ col) {
    int e = blockIdx.x * 256 + threadIdx.x;
    if (e < N_EDGES) {
        int p = atomicAdd(&cur[dst[e]], 1);
        col[p] = src[e];
    }
}

__global__ void k_wbf16(const float* __restrict__ w, short* __restrict__ wb) {
    int i = blockIdx.x * 256 + threadIdx.x;
    if (i < D * D) wb[i] = f2b(w[i]);
}

// ---- y = bf16(x) @ W^T, stored bf16. Verified m92 B^T MFMA pattern. ----
// 4 waves/block; wave w: 16 rows x cols [w*32, w*32+32); K=128 in 4 steps.
__global__ __launch_bounds__(256) void k_xw(const float* __restrict__ x,
                                            const short* __restrict__ wb,
                                            short* __restrict__ y) {
    int t = threadIdx.x;
    int wave = t >> 6, lane = t & 63;
    int row0 = blockIdx.x * 16;   // 3125 * 16 = 50000 exact
    int c0 = wave * 32;
    int lr = lane & 15;
    int lk = (lane >> 4) * 8;
    f32x4 acc0 = {0.f, 0.f, 0.f, 0.f};
    f32x4 acc1 = {0.f, 0.f, 0.f, 0.f};
    const float* ap  = x + (size_t)(row0 + lr) * D + lk;
    const short* bp0 = wb + (size_t)(c0 + lr) * D + lk;
    const short* bp1 = wb + (size_t)(c0 + 16 + lr) * D + lk;
    #pragma unroll
    for (int ks = 0; ks < 4; ++ks) {
        f32x4 xa = *(const f32x4*)(ap + ks * 32);
        f32x4 xb = *(const f32x4*)(ap + ks * 32 + 4);
        bf16x8 a;
        #pragma unroll
        for (int q = 0; q < 4; ++q) { a[q] = f2b(xa[q]); a[q + 4] = f2b(xb[q]); }
        bf16x8 b0 = *(const bf16x8*)(bp0 + ks * 32);
        bf16x8 b1 = *(const bf16x8*)(bp1 + ks * 32);
        acc0 = __builtin_amdgcn_mfma_f32_16x16x32_bf16(a, b0, acc0, 0, 0, 0);
        acc1 = __builtin_amdgcn_mfma_f32_16x16x32_bf16(a, b1, acc1, 0, 0, 0);
    }
    // D layout: col = lane&15, row = (lane>>4)*4 + i  (verified by R2 pass)
    int orow = row0 + (lane >> 4) * 4;
    int oc0 = c0 + lr, oc1 = c0 + 16 + lr;
    #pragma unroll
    for (int i = 0; i < 4; ++i) {
        y[(size_t)(orow + i) * D + oc0] = f2b(acc0[i]);
        y[(size_t)(orow + i) * D + oc1] = f2b(acc1[i]);
    }
}

// ---- gather on y (bf16): 16 lanes per node, 16B/lane = 256B row ----
// out[n] = dd*( sum_e dinv[s]*y[s] + dd*y[n] ) + bias
__global__ __launch_bounds__(256) void k_gather(const short* __restrict__ y,
                                                const float* __restrict__ dinv,
                                                const int* __restrict__ rowptr,
                                                const int* __restrict__ deg,
                                                const int* __restrict__ col,
                                                const float* __restrict__ bias,
                                                float* __restrict__ out) {
    int tid = blockIdx.x * 256 + threadIdx.x;
    int n = tid >> 4;            // node id (16 lanes per node)
    int sub = threadIdx.x & 15;  // 8-channel chunk: channels sub*8 .. sub*8+7
    if (n >= N_NODES) return;
    float dd = dinv[n];
    bf16x8 self = *(const bf16x8*)(y + (size_t)n * D + sub * 8);
    float acc[8];
    #pragma unroll
    for (int q = 0; q < 8; ++q) acc[q] = dd * b2f(self[q]);
    int rp = rowptr[n];
    int dn = deg[n];
    for (int j = 0; j < dn; ++j) {
        int s = col[rp + j];
        float ds = dinv[s];
        bf16x8 v = *(const bf16x8*)(y + (size_t)s * D + sub * 8);
        #pragma unroll
        for (int q = 0; q < 8; ++q) acc[q] += ds * b2f(v[q]);
    }
    const float4* bch = (const float4*)(bias + sub * 8);
    float4 b0 = bch[0], b1 = bch[1];
    float4 o0, o1;
    o0.x = dd * acc[0] + b0.x; o0.y = dd * acc[1] + b0.y;
    o0.z = dd * acc[2] + b0.z; o0.w = dd * acc[3] + b0.w;
    o1.x = dd * acc[4] + b1.x; o1.y = dd * acc[5] + b1.y;
    o1.z = dd * acc[6] + b1.z; o1.w = dd * acc[7] + b1.w;
    float4* op = (float4*)(out + (size_t)n * D + sub * 8);
    op[0] = o0; op[1] = o1;
}

extern "C" void kernel_launch(void* const* d_in, const int* in_sizes, int n_in,
                              void* d_out, int out_size, void* d_ws, size_t ws_size,
                              hipStream_t stream) {
    const float* x    = (const float*)d_in[0];
    const int*   ei   = (const int*)d_in[1];   // [2, E]: row0=src, row1=dst
    const float* w    = (const float*)d_in[2];
    const float* bias = (const float*)d_in[3];
    float* out = (float*)d_out;

    const int* src = ei;
    const int* dst = ei + N_EDGES;

    // workspace carve (all regions fully rewritten every call)
    char* p = (char*)d_ws;
    short* y    = (short*)p;  p += (size_t)N_NODES * D * 2;  // 12.8 MB
    short* wb   = (short*)p;  p += (size_t)D * D * 2;        // 32 KB
    int* deg    = (int*)p;    p += (size_t)N_NODES * 4;
    float* dinv = (float*)p;  p += (size_t)N_NODES * 4;
    int* rowptr = (int*)p;    p += (size_t)N_NODES * 4;
    int* cur    = (int*)p;    p += (size_t)N_NODES * 4;
    int* part   = (int*)p;    p += (size_t)N_NODES * 4;
    int* col    = (int*)p;    p += (size_t)N_EDGES * 4;      // 2.5 MB
    int* bsum   = (int*)p;    p += 256 * 4;
    int* boff   = (int*)p;    p += 256 * 4;

    hipMemsetAsync(deg, 0, N_NODES * sizeof(int), stream);
    k_deg<<<(N_EDGES + 255) / 256, 256, 0, stream>>>(dst, deg);
    k_scan1<<<NB_SCAN, SCAN_T, 0, stream>>>(deg, part, bsum, dinv);
    k_scan2<<<1, 64, 0, stream>>>(bsum, boff);
    k_scan3<<<(N_NODES + 255) / 256, 256, 0, stream>>>(part, boff, rowptr, cur);
    k_fill<<<(N_EDGES + 255) / 256, 256, 0, stream>>>(src, dst, cur, col);
    k_wbf16<<<(D * D + 255) / 256, 256, 0, stream>>>(w, wb);
    k_xw<<<N_NODES / 16, 256, 0, stream>>>(x, wb, y);
    k_gather<<<((N_NODES * 16) + 255) / 256, 256, 0, stream>>>(y, dinv, rowptr, deg, col, bias, out);
}

// Round 5
// 145.522 us; speedup vs baseline: 7.7894x; 1.0033x over previous
//
#include <hip/hip_runtime.h>
#include <hip/hip_bf16.h>

#define N_NODES 50000
#define N_EDGES 625000
#define D 128
#define SCAN_T 256
#define SCAN_ELEMS 1024
#define NB_SCAN ((N_NODES + SCAN_ELEMS - 1) / SCAN_ELEMS)  // 49

typedef __attribute__((ext_vector_type(8))) short bf16x8;
typedef __attribute__((ext_vector_type(4))) float f32x4;

__device__ __forceinline__ float b2f(short s) {
    unsigned u = ((unsigned)(unsigned short)s) << 16;
    return __uint_as_float(u);
}
__device__ __forceinline__ short f2b(float f) {
    union { __hip_bfloat16 h; short s; } cv;
    cv.h = __float2bfloat16(f);
    return cv.s;
}

// ---- zero deg (replaces 45us rocclr fillBuffer) ----
__global__ void k_zero(int* __restrict__ deg) {
    int i = blockIdx.x * 256 + threadIdx.x;
    if (i < N_NODES) deg[i] = 0;
}

// ---- in-degree histogram on dst ----
__global__ void k_deg(const int* __restrict__ dst, int* __restrict__ deg) {
    int e = blockIdx.x * 256 + threadIdx.x;
    if (e < N_EDGES) atomicAdd(&deg[dst[e]], 1);
}

// ---- scan step 1 (+ fused dinv) ----
__global__ void k_scan1(const int* __restrict__ deg, int* __restrict__ part,
                        int* __restrict__ bsum, float* __restrict__ dinv) {
    __shared__ int ts[SCAN_T];
    int t = threadIdx.x;
    int base = blockIdx.x * SCAN_ELEMS + t * 4;
    int v0 = 0, v1 = 0, v2 = 0, v3 = 0;
    if (base + 0 < N_NODES) v0 = deg[base + 0];
    if (base + 1 < N_NODES) v1 = deg[base + 1];
    if (base + 2 < N_NODES) v2 = deg[base + 2];
    if (base + 3 < N_NODES) v3 = deg[base + 3];
    if (base + 0 < N_NODES) dinv[base + 0] = rsqrtf((float)(v0 + 1));
    if (base + 1 < N_NODES) dinv[base + 1] = rsqrtf((float)(v1 + 1));
    if (base + 2 < N_NODES) dinv[base + 2] = rsqrtf((float)(v2 + 1));
    if (base + 3 < N_NODES) dinv[base + 3] = rsqrtf((float)(v3 + 1));
    int s = v0 + v1 + v2 + v3;
    ts[t] = s;
    __syncthreads();
    for (int off = 1; off < SCAN_T; off <<= 1) {
        int tmp = 0;
        if (t >= off) tmp = ts[t - off];
        __syncthreads();
        if (t >= off) ts[t] += tmp;
        __syncthreads();
    }
    int excl = ts[t] - s;
    if (base + 0 < N_NODES) part[base + 0] = excl;
    if (base + 1 < N_NODES) part[base + 1] = excl + v0;
    if (base + 2 < N_NODES) part[base + 2] = excl + v0 + v1;
    if (base + 3 < N_NODES) part[base + 3] = excl + v0 + v1 + v2;
    if (t == SCAN_T - 1) bsum[blockIdx.x] = ts[t];
}

// ---- scan step 2: single-wave shfl prefix ----
__global__ void k_scan2(const int* __restrict__ bsum, int* __restrict__ boff) {
    int lane = threadIdx.x;  // 64 lanes, NB_SCAN=49 <= 64
    int v = (lane < NB_SCAN) ? bsum[lane] : 0;
    int orig = v;
    #pragma unroll
    for (int off = 1; off < 64; off <<= 1) {
        int tmp = __shfl_up(v, off);
        if (lane >= off) v += tmp;
    }
    if (lane < NB_SCAN) boff[lane] = v - orig;  // exclusive
}

__global__ void k_scan3(const int* __restrict__ part, const int* __restrict__ boff,
                        int* __restrict__ rowptr, int* __restrict__ cur) {
    int i = blockIdx.x * 256 + threadIdx.x;
    if (i < N_NODES) {
        int r = part[i] + boff[i / SCAN_ELEMS];
        rowptr[i] = r;
        cur[i] = r;
    }
}

// ---- CSR fill ----
__global__ void k_fill(const int* __restrict__ src, const int* __restrict__ dst,
                       int* __restrict__ cur, int* __restrict__ col) {
    int e = blockIdx.x * 256 + threadIdx.x;
    if (e < N_EDGES) {
        int p = atomicAdd(&cur[dst[e]], 1);
        col[p] = src[e];
    }
}

__global__ void k_wbf16(const float* __restrict__ w, short* __restrict__ wb) {
    int i = blockIdx.x * 256 + threadIdx.x;
    if (i < D * D) wb[i] = f2b(w[i]);
}

// ---- y = bf16(x) @ W^T, stored bf16. Verified m92 B^T MFMA pattern. ----
__global__ __launch_bounds__(256) void k_xw(const float* __restrict__ x,
                                            const short* __restrict__ wb,
                                            short* __restrict__ y) {
    int t = threadIdx.x;
    int wave = t >> 6, lane = t & 63;
    int row0 = blockIdx.x * 16;   // 3125 * 16 = 50000 exact
    int c0 = wave * 32;
    int lr = lane & 15;
    int lk = (lane >> 4) * 8;
    f32x4 acc0 = {0.f, 0.f, 0.f, 0.f};
    f32x4 acc1 = {0.f, 0.f, 0.f, 0.f};
    const float* ap  = x + (size_t)(row0 + lr) * D + lk;
    const short* bp0 = wb + (size_t)(c0 + lr) * D + lk;
    const short* bp1 = wb + (size_t)(c0 + 16 + lr) * D + lk;
    #pragma unroll
    for (int ks = 0; ks < 4; ++ks) {
        f32x4 xa = *(const f32x4*)(ap + ks * 32);
        f32x4 xb = *(const f32x4*)(ap + ks * 32 + 4);
        bf16x8 a;
        #pragma unroll
        for (int q = 0; q < 4; ++q) { a[q] = f2b(xa[q]); a[q + 4] = f2b(xb[q]); }
        bf16x8 b0 = *(const bf16x8*)(bp0 + ks * 32);
        bf16x8 b1 = *(const bf16x8*)(bp1 + ks * 32);
        acc0 = __builtin_amdgcn_mfma_f32_16x16x32_bf16(a, b0, acc0, 0, 0, 0);
        acc1 = __builtin_amdgcn_mfma_f32_16x16x32_bf16(a, b1, acc1, 0, 0, 0);
    }
    int orow = row0 + (lane >> 4) * 4;
    int oc0 = c0 + lr, oc1 = c0 + 16 + lr;
    #pragma unroll
    for (int i = 0; i < 4; ++i) {
        y[(size_t)(orow + i) * D + oc0] = f2b(acc0[i]);
        y[(size_t)(orow + i) * D + oc1] = f2b(acc1[i]);
    }
}

// ---- gather on y (bf16): 16 lanes per node, 16B/lane = 256B row ----
__global__ __launch_bounds__(256) void k_gather(const short* __restrict__ y,
                                                const float* __restrict__ dinv,
                                                const int* __restrict__ rowptr,
                                                const int* __restrict__ deg,
                                                const int* __restrict__ col,
                                                const float* __restrict__ bias,
                                                float* __restrict__ out) {
    int tid = blockIdx.x * 256 + threadIdx.x;
    int n = tid >> 4;            // node id (16 lanes per node)
    int sub = threadIdx.x & 15;  // 8-channel chunk
    if (n >= N_NODES) return;
    float dd = dinv[n];
    bf16x8 self = *(const bf16x8*)(y + (size_t)n * D + sub * 8);
    float acc[8];
    #pragma unroll
    for (int q = 0; q < 8; ++q) acc[q] = dd * b2f(self[q]);
    int rp = rowptr[n];
    int dn = deg[n];
    for (int j = 0; j < dn; ++j) {
        int s = col[rp + j];
        float ds = dinv[s];
        bf16x8 v = *(const bf16x8*)(y + (size_t)s * D + sub * 8);
        #pragma unroll
        for (int q = 0; q < 8; ++q) acc[q] += ds * b2f(v[q]);
    }
    const float4* bch = (const float4*)(bias + sub * 8);
    float4 b0 = bch[0], b1 = bch[1];
    float4 o0, o1;
    o0.x = dd * acc[0] + b0.x; o0.y = dd * acc[1] + b0.y;
    o0.z = dd * acc[2] + b0.z; o0.w = dd * acc[3] + b0.w;
    o1.x = dd * acc[4] + b1.x; o1.y = dd * acc[5] + b1.y;
    o1.z = dd * acc[6] + b1.z; o1.w = dd * acc[7] + b1.w;
    float4* op = (float4*)(out + (size_t)n * D + sub * 8);
    op[0] = o0; op[1] = o1;
}

extern "C" void kernel_launch(void* const* d_in, const int* in_sizes, int n_in,
                              void* d_out, int out_size, void* d_ws, size_t ws_size,
                              hipStream_t stream) {
    const float* x    = (const float*)d_in[0];
    const int*   ei   = (const int*)d_in[1];   // [2, E]: row0=src, row1=dst
    const float* w    = (const float*)d_in[2];
    const float* bias = (const float*)d_in[3];
    float* out = (float*)d_out;

    const int* src = ei;
    const int* dst = ei + N_EDGES;

    // workspace carve (all regions fully rewritten every call)
    char* p = (char*)d_ws;
    short* y    = (short*)p;  p += (size_t)N_NODES * D * 2;  // 12.8 MB
    short* wb   = (short*)p;  p += (size_t)D * D * 2;        // 32 KB
    int* deg    = (int*)p;    p += (size_t)N_NODES * 4;
    float* dinv = (float*)p;  p += (size_t)N_NODES * 4;
    int* rowptr = (int*)p;    p += (size_t)N_NODES * 4;
    int* cur    = (int*)p;    p += (size_t)N_NODES * 4;
    int* part   = (int*)p;    p += (size_t)N_NODES * 4;
    int* col    = (int*)p;    p += (size_t)N_EDGES * 4;      // 2.5 MB
    int* bsum   = (int*)p;    p += 256 * 4;
    int* boff   = (int*)p;    p += 256 * 4;

    k_zero<<<(N_NODES + 255) / 256, 256, 0, stream>>>(deg);
    k_deg<<<(N_EDGES + 255) / 256, 256, 0, stream>>>(dst, deg);
    k_scan1<<<NB_SCAN, SCAN_T, 0, stream>>>(deg, part, bsum, dinv);
    k_scan2<<<1, 64, 0, stream>>>(bsum, boff);
    k_scan3<<<(N_NODES + 255) / 256, 256, 0, stream>>>(part, boff, rowptr, cur);
    k_fill<<<(N_EDGES + 255) / 256, 256, 0, stream>>>(src, dst, cur, col);
    k_wbf16<<<(D * D + 255) / 256, 256, 0, stream>>>(w, wb);
    k_xw<<<N_NODES / 16, 256, 0, stream>>>(x, wb, y);
    k_gather<<<((N_NODES * 16) + 255) / 256, 256, 0, stream>>>(y, dinv, rowptr, deg, col, bias, out);
}

// Round 6
// 142.896 us; speedup vs baseline: 7.9325x; 1.0184x over previous
//
#include <hip/hip_runtime.h>
#include <hip/hip_bf16.h>

#define N_NODES 50000
#define N_EDGES 625000
#define D 128
#define SCAN_T 256
#define SCAN_ELEMS 1024
#define NB_SCAN ((N_NODES + SCAN_ELEMS - 1) / SCAN_ELEMS)  // 49
#define NRANGE 8
#define RSPAN (N_NODES / NRANGE)      // 6250 exact
#define PART_BLOCKS 1024              // 128 blocks per range
#define PART_STRIDE ((PART_BLOCKS / NRANGE) * 256)  // 32768 threads per range-group

typedef __attribute__((ext_vector_type(8))) short bf16x8;
typedef __attribute__((ext_vector_type(4))) float f32x4;

__device__ __forceinline__ float b2f(short s) {
    unsigned u = ((unsigned)(unsigned short)s) << 16;
    return __uint_as_float(u);
}
__device__ __forceinline__ short f2b(float f) {
    union { __hip_bfloat16 h; short s; } cv;
    cv.h = __float2bfloat16(f);
    return cv.s;
}

// ---- zero deg ----
__global__ void k_zero(int* __restrict__ deg) {
    int i = blockIdx.x * 256 + threadIdx.x;
    if (i < N_NODES) deg[i] = 0;
}

// ---- in-degree histogram, XCD-range-partitioned ----
// group g = blockIdx&7 handles dst in [g*RSPAN, (g+1)*RSPAN): deg lines stay in one XCD L2.
__global__ __launch_bounds__(256) void k_deg(const int* __restrict__ dst,
                                             int* __restrict__ deg) {
    int g = blockIdx.x & 7;
    int bg = blockIdx.x >> 3;  // 0..127 within group
    int lo = g * RSPAN, hi = lo + RSPAN;
    for (int e = bg * 256 + threadIdx.x; e < N_EDGES; e += PART_STRIDE) {
        int d = dst[e];
        if (d >= lo && d < hi) atomicAdd(&deg[d], 1);
    }
}

// ---- scan step 1 (+ fused dinv) ----
__global__ void k_scan1(const int* __restrict__ deg, int* __restrict__ part,
                        int* __restrict__ bsum, float* __restrict__ dinv) {
    __shared__ int ts[SCAN_T];
    int t = threadIdx.x;
    int base = blockIdx.x * SCAN_ELEMS + t * 4;
    int v0 = 0, v1 = 0, v2 = 0, v3 = 0;
    if (base + 0 < N_NODES) v0 = deg[base + 0];
    if (base + 1 < N_NODES) v1 = deg[base + 1];
    if (base + 2 < N_NODES) v2 = deg[base + 2];
    if (base + 3 < N_NODES) v3 = deg[base + 3];
    if (base + 0 < N_NODES) dinv[base + 0] = rsqrtf((float)(v0 + 1));
    if (base + 1 < N_NODES) dinv[base + 1] = rsqrtf((float)(v1 + 1));
    if (base + 2 < N_NODES) dinv[base + 2] = rsqrtf((float)(v2 + 1));
    if (base + 3 < N_NODES) dinv[base + 3] = rsqrtf((float)(v3 + 1));
    int s = v0 + v1 + v2 + v3;
    ts[t] = s;
    __syncthreads();
    for (int off = 1; off < SCAN_T; off <<= 1) {
        int tmp = 0;
        if (t >= off) tmp = ts[t - off];
        __syncthreads();
        if (t >= off) ts[t] += tmp;
        __syncthreads();
    }
    int excl = ts[t] - s;
    if (base + 0 < N_NODES) part[base + 0] = excl;
    if (base + 1 < N_NODES) part[base + 1] = excl + v0;
    if (base + 2 < N_NODES) part[base + 2] = excl + v0 + v1;
    if (base + 3 < N_NODES) part[base + 3] = excl + v0 + v1 + v2;
    if (t == SCAN_T - 1) bsum[blockIdx.x] = ts[t];
}

// ---- scan step 2: single-wave shfl prefix ----
__global__ void k_scan2(const int* __restrict__ bsum, int* __restrict__ boff) {
    int lane = threadIdx.x;  // 64 lanes, NB_SCAN=49 <= 64
    int v = (lane < NB_SCAN) ? bsum[lane] : 0;
    int orig = v;
    #pragma unroll
    for (int off = 1; off < 64; off <<= 1) {
        int tmp = __shfl_up(v, off);
        if (lane >= off) v += tmp;
    }
    if (lane < NB_SCAN) boff[lane] = v - orig;  // exclusive
}

__global__ void k_scan3(const int* __restrict__ part, const int* __restrict__ boff,
                        int* __restrict__ rowptr, int* __restrict__ cur) {
    int i = blockIdx.x * 256 + threadIdx.x;
    if (i < N_NODES) {
        int r = part[i] + boff[i / SCAN_ELEMS];
        rowptr[i] = r;
        cur[i] = r;
    }
}

// ---- CSR fill, XCD-range-partitioned (kills col/cur cross-XCD line ping-pong) ----
__global__ __launch_bounds__(256) void k_fill(const int* __restrict__ src,
                                              const int* __restrict__ dst,
                                              int* __restrict__ cur,
                                              int* __restrict__ col) {
    int g = blockIdx.x & 7;
    int bg = blockIdx.x >> 3;
    int lo = g * RSPAN, hi = lo + RSPAN;
    for (int e = bg * 256 + threadIdx.x; e < N_EDGES; e += PART_STRIDE) {
        int d = dst[e];
        if (d >= lo && d < hi) {
            int p = atomicAdd(&cur[d], 1);
            col[p] = src[e];
        }
    }
}

__global__ void k_wbf16(const float* __restrict__ w, short* __restrict__ wb) {
    int i = blockIdx.x * 256 + threadIdx.x;
    if (i < D * D) wb[i] = f2b(w[i]);
}

// ---- y = bf16(x) @ W^T, stored bf16. Verified m92 B^T MFMA pattern. ----
__global__ __launch_bounds__(256) void k_xw(const float* __restrict__ x,
                                            const short* __restrict__ wb,
                                            short* __restrict__ y) {
    int t = threadIdx.x;
    int wave = t >> 6, lane = t & 63;
    int row0 = blockIdx.x * 16;   // 3125 * 16 = 50000 exact
    int c0 = wave * 32;
    int lr = lane & 15;
    int lk = (lane >> 4) * 8;
    f32x4 acc0 = {0.f, 0.f, 0.f, 0.f};
    f32x4 acc1 = {0.f, 0.f, 0.f, 0.f};
    const float* ap  = x + (size_t)(row0 + lr) * D + lk;
    const short* bp0 = wb + (size_t)(c0 + lr) * D + lk;
    const short* bp1 = wb + (size_t)(c0 + 16 + lr) * D + lk;
    #pragma unroll
    for (int ks = 0; ks < 4; ++ks) {
        f32x4 xa = *(const f32x4*)(ap + ks * 32);
        f32x4 xb = *(const f32x4*)(ap + ks * 32 + 4);
        bf16x8 a;
        #pragma unroll
        for (int q = 0; q < 4; ++q) { a[q] = f2b(xa[q]); a[q + 4] = f2b(xb[q]); }
        bf16x8 b0 = *(const bf16x8*)(bp0 + ks * 32);
        bf16x8 b1 = *(const bf16x8*)(bp1 + ks * 32);
        acc0 = __builtin_amdgcn_mfma_f32_16x16x32_bf16(a, b0, acc0, 0, 0, 0);
        acc1 = __builtin_amdgcn_mfma_f32_16x16x32_bf16(a, b1, acc1, 0, 0, 0);
    }
    int orow = row0 + (lane >> 4) * 4;
    int oc0 = c0 + lr, oc1 = c0 + 16 + lr;
    #pragma unroll
    for (int i = 0; i < 4; ++i) {
        y[(size_t)(orow + i) * D + oc0] = f2b(acc0[i]);
        y[(size_t)(orow + i) * D + oc1] = f2b(acc1[i]);
    }
}

// ---- gather on y (bf16): 16 lanes per node, 16B/lane = 256B row ----
__global__ __launch_bounds__(256) void k_gather(const short* __restrict__ y,
                                                const float* __restrict__ dinv,
                                                const int* __restrict__ rowptr,
                                                const int* __restrict__ deg,
                                                const int* __restrict__ col,
                                                const float* __restrict__ bias,
                                                float* __restrict__ out) {
    int tid = blockIdx.x * 256 + threadIdx.x;
    int n = tid >> 4;            // node id (16 lanes per node)
    int sub = threadIdx.x & 15;  // 8-channel chunk
    if (n >= N_NODES) return;
    float dd = dinv[n];
    bf16x8 self = *(const bf16x8*)(y + (size_t)n * D + sub * 8);
    float acc[8];
    #pragma unroll
    for (int q = 0; q < 8; ++q) acc[q] = dd * b2f(self[q]);
    int rp = rowptr[n];
    int dn = deg[n];
    for (int j = 0; j < dn; ++j) {
        int s = col[rp + j];
        float ds = dinv[s];
        bf16x8 v = *(const bf16x8*)(y + (size_t)s * D + sub * 8);
        #pragma unroll
        for (int q = 0; q < 8; ++q) acc[q] += ds * b2f(v[q]);
    }
    const float4* bch = (const float4*)(bias + sub * 8);
    float4 b0 = bch[0], b1 = bch[1];
    float4 o0, o1;
    o0.x = dd * acc[0] + b0.x; o0.y = dd * acc[1] + b0.y;
    o0.z = dd * acc[2] + b0.z; o0.w = dd * acc[3] + b0.w;
    o1.x = dd * acc[4] + b1.x; o1.y = dd * acc[5] + b1.y;
    o1.z = dd * acc[6] + b1.z; o1.w = dd * acc[7] + b1.w;
    float4* op = (float4*)(out + (size_t)n * D + sub * 8);
    op[0] = o0; op[1] = o1;
}

extern "C" void kernel_launch(void* const* d_in, const int* in_sizes, int n_in,
                              void* d_out, int out_size, void* d_ws, size_t ws_size,
                              hipStream_t stream) {
    const float* x    = (const float*)d_in[0];
    const int*   ei   = (const int*)d_in[1];   // [2, E]: row0=src, row1=dst
    const float* w    = (const float*)d_in[2];
    const float* bias = (const float*)d_in[3];
    float* out = (float*)d_out;

    const int* src = ei;
    const int* dst = ei + N_EDGES;

    // workspace carve (all regions fully rewritten every call)
    char* p = (char*)d_ws;
    short* y    = (short*)p;  p += (size_t)N_NODES * D * 2;  // 12.8 MB
    short* wb   = (short*)p;  p += (size_t)D * D * 2;        // 32 KB
    int* deg    = (int*)p;    p += (size_t)N_NODES * 4;
    float* dinv = (float*)p;  p += (size_t)N_NODES * 4;
    int* rowptr = (int*)p;    p += (size_t)N_NODES * 4;
    int* cur    = (int*)p;    p += (size_t)N_NODES * 4;
    int* part   = (int*)p;    p += (size_t)N_NODES * 4;
    int* col    = (int*)p;    p += (size_t)N_EDGES * 4;      // 2.5 MB
    int* bsum   = (int*)p;    p += 256 * 4;
    int* boff   = (int*)p;    p += 256 * 4;

    k_zero<<<(N_NODES + 255) / 256, 256, 0, stream>>>(deg);
    k_deg<<<PART_BLOCKS, 256, 0, stream>>>(dst, deg);
    k_scan1<<<NB_SCAN, SCAN_T, 0, stream>>>(deg, part, bsum, dinv);
    k_scan2<<<1, 64, 0, stream>>>(bsum, boff);
    k_scan3<<<(N_NODES + 255) / 256, 256, 0, stream>>>(part, boff, rowptr, cur);
    k_fill<<<PART_BLOCKS, 256, 0, stream>>>(src, dst, cur, col);
    k_wbf16<<<(D * D + 255) / 256, 256, 0, stream>>>(w, wb);
    k_xw<<<N_NODES / 16, 256, 0, stream>>>(x, wb, y);
    k_gather<<<((N_NODES * 16) + 255) / 256, 256, 0, stream>>>(y, dinv, rowptr, deg, col, bias, out);
}

// Round 7
// 140.196 us; speedup vs baseline: 8.0853x; 1.0193x over previous
//
#include <hip/hip_runtime.h>
#include <hip/hip_bf16.h>

#define N_NODES 50000
#define N_EDGES 625000
#define D 128
#define SCAN_T 256
#define SCAN_ELEMS 1024
#define NB_SCAN ((N_NODES + SCAN_ELEMS - 1) / SCAN_ELEMS)  // 49
#define NRANGE 8
#define RSPAN (N_NODES / NRANGE)      // 6250 exact
#define PART_BLOCKS 1024              // 128 blocks per range
#define PART_STRIDE ((PART_BLOCKS / NRANGE) * 256)  // 32768 threads per range-group

typedef __attribute__((ext_vector_type(8))) short bf16x8;
typedef __attribute__((ext_vector_type(4))) float f32x4;

__device__ __forceinline__ float b2f(short s) {
    unsigned u = ((unsigned)(unsigned short)s) << 16;
    return __uint_as_float(u);
}
__device__ __forceinline__ short f2b(float f) {
    union { __hip_bfloat16 h; short s; } cv;
    cv.h = __float2bfloat16(f);
    return cv.s;
}

// ---- zero deg ----
__global__ void k_zero(int* __restrict__ deg) {
    int i = blockIdx.x * 256 + threadIdx.x;
    if (i < N_NODES) deg[i] = 0;
}

// ---- in-degree histogram, XCD-range-partitioned ----
__global__ __launch_bounds__(256) void k_deg(const int* __restrict__ dst,
                                             int* __restrict__ deg) {
    int g = blockIdx.x & 7;
    int bg = blockIdx.x >> 3;  // 0..127 within group
    int lo = g * RSPAN, hi = lo + RSPAN;
    for (int e = bg * 256 + threadIdx.x; e < N_EDGES; e += PART_STRIDE) {
        int d = dst[e];
        if (d >= lo && d < hi) atomicAdd(&deg[d], 1);
    }
}

// ---- scan step 1 (+ fused dinv) ----
__global__ void k_scan1(const int* __restrict__ deg, int* __restrict__ part,
                        int* __restrict__ bsum, float* __restrict__ dinv) {
    __shared__ int ts[SCAN_T];
    int t = threadIdx.x;
    int base = blockIdx.x * SCAN_ELEMS + t * 4;
    int v0 = 0, v1 = 0, v2 = 0, v3 = 0;
    if (base + 0 < N_NODES) v0 = deg[base + 0];
    if (base + 1 < N_NODES) v1 = deg[base + 1];
    if (base + 2 < N_NODES) v2 = deg[base + 2];
    if (base + 3 < N_NODES) v3 = deg[base + 3];
    if (base + 0 < N_NODES) dinv[base + 0] = rsqrtf((float)(v0 + 1));
    if (base + 1 < N_NODES) dinv[base + 1] = rsqrtf((float)(v1 + 1));
    if (base + 2 < N_NODES) dinv[base + 2] = rsqrtf((float)(v2 + 1));
    if (base + 3 < N_NODES) dinv[base + 3] = rsqrtf((float)(v3 + 1));
    int s = v0 + v1 + v2 + v3;
    ts[t] = s;
    __syncthreads();
    for (int off = 1; off < SCAN_T; off <<= 1) {
        int tmp = 0;
        if (t >= off) tmp = ts[t - off];
        __syncthreads();
        if (t >= off) ts[t] += tmp;
        __syncthreads();
    }
    int excl = ts[t] - s;
    if (base + 0 < N_NODES) part[base + 0] = excl;
    if (base + 1 < N_NODES) part[base + 1] = excl + v0;
    if (base + 2 < N_NODES) part[base + 2] = excl + v0 + v1;
    if (base + 3 < N_NODES) part[base + 3] = excl + v0 + v1 + v2;
    if (t == SCAN_T - 1) bsum[blockIdx.x] = ts[t];
}

// ---- scan step 3 (scan2 folded in: each block recomputes the 49-wide
//      block-offset prefix from bsum — 49 L2-hot loads + one wave shfl scan) ----
__global__ void k_scan3(const int* __restrict__ part, const int* __restrict__ bsum,
                        int* __restrict__ rowptr, int* __restrict__ cur) {
    __shared__ int s_boff[NB_SCAN];
    if (threadIdx.x < 64) {
        int lane = threadIdx.x;
        int v = (lane < NB_SCAN) ? bsum[lane] : 0;
        int orig = v;
        #pragma unroll
        for (int off = 1; off < 64; off <<= 1) {
            int tmp = __shfl_up(v, off);
            if (lane >= off) v += tmp;
        }
        if (lane < NB_SCAN) s_boff[lane] = v - orig;  // exclusive
    }
    __syncthreads();
    int i = blockIdx.x * 256 + threadIdx.x;
    if (i < N_NODES) {
        int r = part[i] + s_boff[i / SCAN_ELEMS];
        rowptr[i] = r;
        cur[i] = r;
    }
}

// ---- CSR fill, XCD-range-partitioned ----
__global__ __launch_bounds__(256) void k_fill(const int* __restrict__ src,
                                              const int* __restrict__ dst,
                                              int* __restrict__ cur,
                                              int* __restrict__ col) {
    int g = blockIdx.x & 7;
    int bg = blockIdx.x >> 3;
    int lo = g * RSPAN, hi = lo + RSPAN;
    for (int e = bg * 256 + threadIdx.x; e < N_EDGES; e += PART_STRIDE) {
        int d = dst[e];
        if (d >= lo && d < hi) {
            int p = atomicAdd(&cur[d], 1);
            col[p] = src[e];
        }
    }
}

// ---- y = bf16(x) @ W^T, stored bf16; W converted f32->bf16 in-register ----
__global__ __launch_bounds__(256) void k_xw(const float* __restrict__ x,
                                            const float* __restrict__ w,
                                            short* __restrict__ y) {
    int t = threadIdx.x;
    int wave = t >> 6, lane = t & 63;
    int row0 = blockIdx.x * 16;   // 3125 * 16 = 50000 exact
    int c0 = wave * 32;
    int lr = lane & 15;
    int lk = (lane >> 4) * 8;
    f32x4 acc0 = {0.f, 0.f, 0.f, 0.f};
    f32x4 acc1 = {0.f, 0.f, 0.f, 0.f};
    const float* ap  = x + (size_t)(row0 + lr) * D + lk;
    const float* wp0 = w + (size_t)(c0 + lr) * D + lk;
    const float* wp1 = w + (size_t)(c0 + 16 + lr) * D + lk;
    #pragma unroll
    for (int ks = 0; ks < 4; ++ks) {
        f32x4 xa = *(const f32x4*)(ap + ks * 32);
        f32x4 xb = *(const f32x4*)(ap + ks * 32 + 4);
        f32x4 wa0 = *(const f32x4*)(wp0 + ks * 32);
        f32x4 wb0 = *(const f32x4*)(wp0 + ks * 32 + 4);
        f32x4 wa1 = *(const f32x4*)(wp1 + ks * 32);
        f32x4 wb1 = *(const f32x4*)(wp1 + ks * 32 + 4);
        bf16x8 a, b0, b1;
        #pragma unroll
        for (int q = 0; q < 4; ++q) {
            a[q]  = f2b(xa[q]);  a[q + 4]  = f2b(xb[q]);
            b0[q] = f2b(wa0[q]); b0[q + 4] = f2b(wb0[q]);
            b1[q] = f2b(wa1[q]); b1[q + 4] = f2b(wb1[q]);
        }
        acc0 = __builtin_amdgcn_mfma_f32_16x16x32_bf16(a, b0, acc0, 0, 0, 0);
        acc1 = __builtin_amdgcn_mfma_f32_16x16x32_bf16(a, b1, acc1, 0, 0, 0);
    }
    int orow = row0 + (lane >> 4) * 4;
    int oc0 = c0 + lr, oc1 = c0 + 16 + lr;
    #pragma unroll
    for (int i = 0; i < 4; ++i) {
        y[(size_t)(orow + i) * D + oc0] = f2b(acc0[i]);
        y[(size_t)(orow + i) * D + oc1] = f2b(acc1[i]);
    }
}

// ---- gather on y (bf16): 16 lanes/node, 4-way pipelined neighbor loop ----
__global__ __launch_bounds__(256) void k_gather(const short* __restrict__ y,
                                                const float* __restrict__ dinv,
                                                const int* __restrict__ rowptr,
                                                const int* __restrict__ deg,
                                                const int* __restrict__ col,
                                                const float* __restrict__ bias,
                                                float* __restrict__ out) {
    int tid = blockIdx.x * 256 + threadIdx.x;
    int n = tid >> 4;            // node id (16 lanes per node)
    int sub = threadIdx.x & 15;  // 8-channel chunk
    if (n >= N_NODES) return;
    float dd = dinv[n];
    bf16x8 self = *(const bf16x8*)(y + (size_t)n * D + sub * 8);
    float acc0[8], acc1[8];
    #pragma unroll
    for (int q = 0; q < 8; ++q) { acc0[q] = dd * b2f(self[q]); acc1[q] = 0.f; }
    int rp = rowptr[n];
    int dn = deg[n];
    int j = 0;
    // 4 independent row loads in flight per iteration
    for (; j + 4 <= dn; j += 4) {
        int s0 = col[rp + j + 0];
        int s1 = col[rp + j + 1];
        int s2 = col[rp + j + 2];
        int s3 = col[rp + j + 3];
        float ds0 = dinv[s0], ds1 = dinv[s1], ds2 = dinv[s2], ds3 = dinv[s3];
        bf16x8 v0 = *(const bf16x8*)(y + (size_t)s0 * D + sub * 8);
        bf16x8 v1 = *(const bf16x8*)(y + (size_t)s1 * D + sub * 8);
        bf16x8 v2 = *(const bf16x8*)(y + (size_t)s2 * D + sub * 8);
        bf16x8 v3 = *(const bf16x8*)(y + (size_t)s3 * D + sub * 8);
        #pragma unroll
        for (int q = 0; q < 8; ++q) {
            acc0[q] += ds0 * b2f(v0[q]) + ds2 * b2f(v2[q]);
            acc1[q] += ds1 * b2f(v1[q]) + ds3 * b2f(v3[q]);
        }
    }
    for (; j < dn; ++j) {
        int s0 = col[rp + j];
        float ds0 = dinv[s0];
        bf16x8 v0 = *(const bf16x8*)(y + (size_t)s0 * D + sub * 8);
        #pragma unroll
        for (int q = 0; q < 8; ++q) acc0[q] += ds0 * b2f(v0[q]);
    }
    const float4* bch = (const float4*)(bias + sub * 8);
    float4 b0 = bch[0], b1 = bch[1];
    float4 o0, o1;
    o0.x = dd * (acc0[0] + acc1[0]) + b0.x; o0.y = dd * (acc0[1] + acc1[1]) + b0.y;
    o0.z = dd * (acc0[2] + acc1[2]) + b0.z; o0.w = dd * (acc0[3] + acc1[3]) + b0.w;
    o1.x = dd * (acc0[4] + acc1[4]) + b1.x; o1.y = dd * (acc0[5] + acc1[5]) + b1.y;
    o1.z = dd * (acc0[6] + acc1[6]) + b1.z; o1.w = dd * (acc0[7] + acc1[7]) + b1.w;
    float4* op = (float4*)(out + (size_t)n * D + sub * 8);
    op[0] = o0; op[1] = o1;
}

extern "C" void kernel_launch(void* const* d_in, const int* in_sizes, int n_in,
                              void* d_out, int out_size, void* d_ws, size_t ws_size,
                              hipStream_t stream) {
    const float* x    = (const float*)d_in[0];
    const int*   ei   = (const int*)d_in[1];   // [2, E]: row0=src, row1=dst
    const float* w    = (const float*)d_in[2];
    const float* bias = (const float*)d_in[3];
    float* out = (float*)d_out;

    const int* src = ei;
    const int* dst = ei + N_EDGES;

    // workspace carve (all regions fully rewritten every call)
    char* p = (char*)d_ws;
    short* y    = (short*)p;  p += (size_t)N_NODES * D * 2;  // 12.8 MB
    int* deg    = (int*)p;    p += (size_t)N_NODES * 4;
    float* dinv = (float*)p;  p += (size_t)N_NODES * 4;
    int* rowptr = (int*)p;    p += (size_t)N_NODES * 4;
    int* cur    = (int*)p;    p += (size_t)N_NODES * 4;
    int* part   = (int*)p;    p += (size_t)N_NODES * 4;
    int* col    = (int*)p;    p += (size_t)N_EDGES * 4;      // 2.5 MB
    int* bsum   = (int*)p;    p += 256 * 4;

    k_zero<<<(N_NODES + 255) / 256, 256, 0, stream>>>(deg);
    k_deg<<<PART_BLOCKS, 256, 0, stream>>>(dst, deg);
    k_scan1<<<NB_SCAN, SCAN_T, 0, stream>>>(deg, part, bsum, dinv);
    k_scan3<<<(N_NODES + 255) / 256, 256, 0, stream>>>(part, bsum, rowptr, cur);
    k_fill<<<PART_BLOCKS, 256, 0, stream>>>(src, dst, cur, col);
    k_xw<<<N_NODES / 16, 256, 0, stream>>>(x, w, y);
    k_gather<<<((N_NODES * 16) + 255) / 256, 256, 0, stream>>>(y, dinv, rowptr, deg, col, bias, out);
}